// Round 8
// baseline (29.511 us; speedup 1.0000x reference)
//
#include <hip/hip_runtime.h>
#include <math.h>

// Problem shape (fixed by the reference setup_inputs): B=4, D=32, H=32, W=16
#define NB 4
#define ND 32
#define NH 32
#define NW 16
#define CPS (ND * NH)            // 1024 (d,h)-columns per sample
#define VPS (CPS * NW)           // 16384 voxels per sample
#define NBLK 64                  // 4 samples x 4 pred-chunks x 4 target-chunks
#define PC 256                   // pred columns per block
#define TC 256                   // target columns per block

// Single-dispatch fused kernel, 64 blocks x 512 threads.
//
// R6/R7 lesson: plain agent-scope stores of partials are parallel/cheap; the
// cost is SERIALIZED same-line far-RMWs (~25ns each at the coherent point).
// R6's flat 256-add ticket ~6us; R7's atomicMax+packed counters doubled the
// RMW count and got slower. This version: 64 blocks, plain stores for
// partials, two-level ticket with every counter on its OWN 128B line ->
// critical path ~16 serialized RMWs (~0.5us).
//
// Phase A (all 512): one thread per column (256 pred + 256 target): 4 float4
//   loads -> 16-bit occupancy mask (pred: logit > 0 <=> sigmoid > 0.5;
//   target: t > 0.5), extremes via ffs/clz -> int2 in LDS.
// Phase B: thread owns pred col (tid>>1) x 128 target cols (2i + (tid&1) ->
//   2-address LDS broadcast, conflict-free). Strength-reduced: (d,h) squares
//   precomputed (8+16 regs, indices i>>4 / i&15), w-part is
//   q = max(pmax - tmin, tmax - pmin) (max |interval endpoint diff|).
// Phase C: plain agent store of block max -> bmax[bid]; vmcnt(0) drain; group
//   ticket (8 groups x 8 adds, 128B-padded) -> final ticket (8 adds, own
//   line). Winner test ((old+1)&7)==0: exactly once per counter per call for
//   ANY start value -> no init, poison- and replay-proof. Winner wave: 64
//   parallel agent loads (bmax[lane]), 16-lane-group reduce per sample,
//   sqrt, mean, store.
__global__ __launch_bounds__(512) void hd_one(
    const float* __restrict__ logits, const float* __restrict__ targets,
    int* bmax, unsigned* gcnt, unsigned* fcnt, float* __restrict__ out) {
    __shared__ int2 s_pe[PC];
    __shared__ int2 s_te[TC];
    __shared__ int s_red[8];
    __shared__ int s_win;

    int bid = blockIdx.x;                 // s*16 + pchunk*4 + tchunk
    int s = bid >> 4;
    int pchunk = (bid >> 2) & 3;
    int tchunk = bid & 3;
    int tid = threadIdx.x;                // 0..511

    // ---- Phase A: column extremes ----
    {
        bool isp = tid < PC;
        int lc = tid & (PC - 1);
        int col = (isp ? pchunk : tchunk) * PC + lc;
        const float4* p4 =
            (const float4*)((isp ? logits : targets) + s * VPS + col * NW);
        float thr = isp ? 0.0f : 0.5f;
        unsigned msk = 0;
#pragma unroll
        for (int j = 0; j < 4; ++j) {
            float4 v = p4[j];
            msk |= (v.x > thr ? 1u : 0u) << (4 * j);
            msk |= (v.y > thr ? 1u : 0u) << (4 * j + 1);
            msk |= (v.z > thr ? 1u : 0u) << (4 * j + 2);
            msk |= (v.w > thr ? 1u : 0u) << (4 * j + 3);
        }
        int2 e = make_int2(msk ? (__ffs(msk) - 1) : 1000,
                           msk ? (31 - __clz(msk)) : -1);
        if (isp) s_pe[lc] = e; else s_te[lc] = e;
    }
    __syncthreads();

    // ---- Phase B: pair max ----
    int lp = tid >> 1;                    // local pred column 0..255
    int tg = tid & 1;
    int2 pe = s_pe[lp];
    int pd = pchunk * 8 + (lp >> 5);      // pcol = pchunk*256 + lp
    int ph = lp & 31;

    int dd2[8], dh2[16];
#pragma unroll
    for (int k = 0; k < 8; ++k) { int d = pd - (tchunk * 8 + k); dd2[k] = d * d; }
#pragma unroll
    for (int j = 0; j < 16; ++j) { int h = ph - (2 * j + tg); dh2[j] = h * h; }

    int best = -1;
#pragma unroll 16
    for (int i = 0; i < 128; ++i) {
        int2 te = s_te[2 * i + tg];
        int q = max(pe.y - te.x, te.y - pe.x);
        int cand = dd2[i >> 4] + dh2[i & 15] + q * q;
        best = (te.y >= 0) ? max(best, cand) : best;   // skip empty target col
    }
    if (pe.y < 0) best = -1;              // empty pred column: discard

    // block reduce (8 waves)
#pragma unroll
    for (int m = 32; m >= 1; m >>= 1) best = max(best, __shfl_xor(best, m, 64));
    if ((tid & 63) == 0) s_red[tid >> 6] = best;
    __syncthreads();

    // ---- Phase C: handshake ----
    if (tid == 0) {
        int mx = s_red[0];
#pragma unroll
        for (int i = 1; i < 8; ++i) mx = max(mx, s_red[i]);
        __hip_atomic_store(&bmax[bid], mx, __ATOMIC_RELAXED,
                           __HIP_MEMORY_SCOPE_AGENT);
        // partial must be at the coherent point before our ticket lands
        asm volatile("s_waitcnt vmcnt(0)" ::: "memory");
        int win = 0;
        int g = bid >> 3;                 // 8 groups of 8 blocks
        unsigned o1 = atomicAdd(&gcnt[g * 32], 1u);     // 128B-padded counter
        if (((o1 + 1u) & 7u) == 0u) {     // last of this group
            asm volatile("s_waitcnt vmcnt(0)" ::: "memory");
            unsigned o2 = atomicAdd(fcnt, 1u);          // own line
            win = (((o2 + 1u) & 7u) == 0u);             // last group overall
        }
        s_win = win;
    }
    __syncthreads();

    if (s_win && tid < 64) {
        // bmax[s*16 + j]: lane l -> sample l>>4, slot l&15
        int m = __hip_atomic_load(&bmax[tid], __ATOMIC_RELAXED,
                                  __HIP_MEMORY_SCOPE_AGENT);
#pragma unroll
        for (int k = 8; k >= 1; k >>= 1) m = max(m, __shfl_xor(m, k, 64));
        float hd = (m < 0) ? INFINITY : sqrtf((float)m);
        // lanes 0,16,32,48 hold samples 0..3
        float ssum = __shfl(hd, 0, 64) + __shfl(hd, 16, 64) +
                     __shfl(hd, 32, 64) + __shfl(hd, 48, 64);
        if (tid == 0) out[0] = ssum * (1.0f / NB);
    }
}

extern "C" void kernel_launch(void* const* d_in, const int* in_sizes, int n_in,
                              void* d_out, int out_size, void* d_ws, size_t ws_size,
                              hipStream_t stream) {
    const float* logits  = (const float*)d_in[0];
    const float* targets = (const float*)d_in[1];
    float* out = (float*)d_out;

    char* ws = (char*)d_ws;               // all no-init (see kernel comment)
    int* bmax = (int*)ws;                                 // 64 ints (256 B)
    unsigned* gcnt = (unsigned*)(ws + 512);               // 8 x 128B-padded
    unsigned* fcnt = (unsigned*)(ws + 512 + 8 * 128);     // own line

    hd_one<<<NBLK, 512, 0, stream>>>(logits, targets, bmax, gcnt, fcnt, out);
}

// Round 9
// 10.919 us; speedup vs baseline: 2.7028x; 2.7028x over previous
//
#include <hip/hip_runtime.h>
#include <math.h>

// Problem shape (fixed by the reference setup_inputs): B=4, D=32, H=32, W=16
#define NB 4
#define ND 32
#define NH 32
#define NW 16
#define CPS (ND * NH)            // 1024 (d,h)-columns per sample
#define VPS (CPS * NW)           // 16384 voxels per sample
#define NBLK 256                 // 4 samples x 8 pred-chunks x 8 target-chunks
#define PC 128                   // pred columns per block
#define TC 128                   // target columns per block

// Single-dispatch fused kernel, full chip (256 blocks x 512 threads).
// Body is R6's verbatim (12.4us total): fully-unrolled phase B keeps dd2/dh2
// in registers (R8 lesson / rule #20: partial unroll -> runtime index ->
// scratch spill -> 29.5us). Only the completion ticket changed vs R6:
// two-level, every counter on its OWN 128B line -> critical path ~32
// serialized far-RMWs (~0.8us) instead of R6's flat 256 on one line (~6us).
//
// Phase A (threads 0..255): one thread per column: 4 float4 loads -> 16-bit
//   occupancy mask (pred: logit > 0 <=> sigmoid > 0.5; target: t > 0.5),
//   extremes via ffs/clz -> int2 in LDS.
// Phase B (all 512): thread owns pred col (tid>>2) x 32 target cols
//   (tg + 4i -> 4-address LDS broadcast, conflict-free). Fully unrolled,
//   strength-reduced: (d,h) squares precomputed (4+8 regs, compile-time
//   indexed), w-part q = max(pmax - tmin, tmax - pmin).
// Phase C (thread 0): plain agent store of block max -> bmax[bid]; vmcnt(0)
//   drain; group ticket (16 groups x 16 adds, 128B-padded) -> final ticket
//   (16 adds, own line). Winner test ((old+1)&15)==0: exactly once per
//   counter per call for ANY start value -> no init, poison/replay-proof.
//   Winner wave: 64 lanes x 4 agent loads of the 256 partials, reduce,
//   sqrt, mean, store.
__global__ __launch_bounds__(512) void hd_one(
    const float* __restrict__ logits, const float* __restrict__ targets,
    int* bmax, unsigned* gcnt, unsigned* fcnt, float* __restrict__ out) {
    __shared__ int2 s_pe[PC];
    __shared__ int2 s_te[TC];
    __shared__ int s_red[8];
    __shared__ int s_win;

    int bid = blockIdx.x;                 // s*64 + pchunk*8 + tchunk
    int s = bid >> 6;
    int pchunk = (bid >> 3) & 7;
    int tchunk = bid & 7;
    int tid = threadIdx.x;                // 0..511

    // ---- Phase A: column extremes (threads 0..255) ----
    if (tid < 256) {
        bool isp = tid < PC;
        int lc = tid & (PC - 1);
        int col = (isp ? pchunk : tchunk) * PC + lc;
        const float4* p4 =
            (const float4*)((isp ? logits : targets) + s * VPS + col * NW);
        float thr = isp ? 0.0f : 0.5f;
        unsigned msk = 0;
#pragma unroll
        for (int j = 0; j < 4; ++j) {
            float4 v = p4[j];
            msk |= (v.x > thr ? 1u : 0u) << (4 * j);
            msk |= (v.y > thr ? 1u : 0u) << (4 * j + 1);
            msk |= (v.z > thr ? 1u : 0u) << (4 * j + 2);
            msk |= (v.w > thr ? 1u : 0u) << (4 * j + 3);
        }
        int2 e = make_int2(msk ? (__ffs(msk) - 1) : 1000,
                           msk ? (31 - __clz(msk)) : -1);
        if (isp) s_pe[lc] = e; else s_te[lc] = e;
    }
    __syncthreads();

    // ---- Phase B: pair max (fully unrolled; register-indexed dd2/dh2) ----
    int lp = tid >> 2;                    // local pred column 0..127
    int tg = tid & 3;
    int2 pe = s_pe[lp];
    int pcol = pchunk * PC + lp;
    int pd = pcol >> 5, ph = pcol & 31;

    int dd2[4], dh2[8];
#pragma unroll
    for (int k = 0; k < 4; ++k) { int d = pd - (tchunk * 4 + k); dd2[k] = d * d; }
#pragma unroll
    for (int j = 0; j < 8; ++j) { int h = ph - (4 * j + tg); dh2[j] = h * h; }

    int best = -1;
#pragma unroll
    for (int i = 0; i < 32; ++i) {
        int2 te = s_te[tg + 4 * i];
        int q = max(pe.y - te.x, te.y - pe.x);
        int cand = dd2[i >> 3] + dh2[i & 7] + q * q;
        best = (te.y >= 0) ? max(best, cand) : best;   // skip empty target col
    }
    if (pe.y < 0) best = -1;              // empty pred column: discard

    // block reduce (8 waves)
#pragma unroll
    for (int m = 32; m >= 1; m >>= 1) best = max(best, __shfl_xor(best, m, 64));
    if ((tid & 63) == 0) s_red[tid >> 6] = best;
    __syncthreads();

    // ---- Phase C: handshake ----
    if (tid == 0) {
        int mx = s_red[0];
#pragma unroll
        for (int i = 1; i < 8; ++i) mx = max(mx, s_red[i]);
        __hip_atomic_store(&bmax[bid], mx, __ATOMIC_RELAXED,
                           __HIP_MEMORY_SCOPE_AGENT);
        // partial must be at the coherent point before our ticket lands
        asm volatile("s_waitcnt vmcnt(0)" ::: "memory");
        int win = 0;
        int g = bid >> 4;                 // 16 groups of 16 blocks
        unsigned o1 = atomicAdd(&gcnt[g * 32], 1u);     // own 128B line
        if (((o1 + 1u) & 15u) == 0u) {    // last of this group
            asm volatile("s_waitcnt vmcnt(0)" ::: "memory");
            unsigned o2 = atomicAdd(fcnt, 1u);          // own line
            win = (((o2 + 1u) & 15u) == 0u) ? 1 : 0;    // last group overall
        }
        s_win = win;
    }
    __syncthreads();

    if (s_win && tid < 64) {
        // lane l holds bids 4l..4l+3; sample = l>>4 (64 bids per sample)
        int b0 = tid * 4;
        int m0 = __hip_atomic_load(&bmax[b0 + 0], __ATOMIC_RELAXED,
                                   __HIP_MEMORY_SCOPE_AGENT);
        int m1 = __hip_atomic_load(&bmax[b0 + 1], __ATOMIC_RELAXED,
                                   __HIP_MEMORY_SCOPE_AGENT);
        int m2 = __hip_atomic_load(&bmax[b0 + 2], __ATOMIC_RELAXED,
                                   __HIP_MEMORY_SCOPE_AGENT);
        int m3 = __hip_atomic_load(&bmax[b0 + 3], __ATOMIC_RELAXED,
                                   __HIP_MEMORY_SCOPE_AGENT);
        int m = max(max(m0, m1), max(m2, m3));
#pragma unroll
        for (int k = 8; k >= 1; k >>= 1) m = max(m, __shfl_xor(m, k, 64));
        float hd = (m < 0) ? INFINITY : sqrtf((float)m);
        // lanes 0,16,32,48 hold samples 0..3
        float ssum = __shfl(hd, 0, 64) + __shfl(hd, 16, 64) +
                     __shfl(hd, 32, 64) + __shfl(hd, 48, 64);
        if (tid == 0) out[0] = ssum * (1.0f / NB);
    }
}

extern "C" void kernel_launch(void* const* d_in, const int* in_sizes, int n_in,
                              void* d_out, int out_size, void* d_ws, size_t ws_size,
                              hipStream_t stream) {
    const float* logits  = (const float*)d_in[0];
    const float* targets = (const float*)d_in[1];
    float* out = (float*)d_out;

    char* ws = (char*)d_ws;               // all no-init (see kernel comment)
    int* bmax = (int*)ws;                                 // 256 ints (1 KB)
    unsigned* gcnt = (unsigned*)(ws + 1024);              // 16 x 128B-padded
    unsigned* fcnt = (unsigned*)(ws + 1024 + 16 * 128);   // own line

    hd_one<<<NBLK, 512, 0, stream>>>(logits, targets, bmax, gcnt, fcnt, out);
}